// Round 2
// baseline (1155.101 us; speedup 1.0000x reference)
//
#include <hip/hip_runtime.h>
#include <math.h>

#define D     512
#define KCB   1024
#define NT    256
#define AS    264            // 256 + 8 pad (ushorts) -> LDS row stride 528 B, 2-way banks (free)
#define EPS2  1e-3f          // candidate window: >= 100x the hi/lo-split error bound (~4e-6)
#define CAND_CAP (1u<<18)

typedef short s8 __attribute__((ext_vector_type(8)));
typedef float f4 __attribute__((ext_vector_type(4)));

__device__ __forceinline__ unsigned short f2bf(float x){
    union { float f; unsigned u; } v; v.f = x;
    unsigned r = v.u + 0x7FFFu + ((v.u >> 16) & 1u);   // RN-even
    return (unsigned short)(r >> 16);
}
__device__ __forceinline__ float bf2f(unsigned short h){
    union { float f; unsigned u; } v; v.u = ((unsigned)h) << 16; return v.f;
}
__device__ __forceinline__ float wsum(float v){
    #pragma unroll
    for (int off = 32; off >= 1; off >>= 1) v += __shfl_xor(v, off, 64);
    return v;
}

// ---------------- K0: zero accumulators (ws re-poisoned 0xAA every call)
__global__ void k_init(unsigned long long* __restrict__ rowwin, float* __restrict__ avg,
                       float* __restrict__ clup, unsigned* __restrict__ cnt,
                       float* __restrict__ sse, int B) {
    int t = threadIdx.x + blockIdx.x * blockDim.x;
    int n = gridDim.x * blockDim.x;
    for (int i = t; i < B; i += n) rowwin[i] = 0ull;
    for (int i = t; i < KCB; i += n) avg[i] = 0.f;
    for (int i = t; i < 256; i += n) clup[i] = 0.f;
    if (t == 0) { cnt[0] = 0u; sse[0] = 0.f; }
}

// ---------------- K1: per-row inverse L2 norms of latents
__global__ __launch_bounds__(NT) void k_norms(const float* __restrict__ lat, float* __restrict__ inv_ws) {
    const int w = threadIdx.x >> 6, lane = threadIdx.x & 63;
    const int row = blockIdx.x * 4 + w;
    const float4* lp = (const float4*)lat + (size_t)row * (D / 4);
    float4 a = lp[lane * 2], b = lp[lane * 2 + 1];
    float ss = a.x*a.x + a.y*a.y + a.z*a.z + a.w*a.w + b.x*b.x + b.y*b.y + b.z*b.z + b.w*b.w;
    ss = wsum(ss);
    if (lane == 0) inv_ws[row] = 1.0f / fmaxf(sqrtf(ss), 1e-12f);
}

// ---------------- K2: normalized codebook: fp32 [K][D] (exact fixup) + bf16 hi/lo [K][D]
__global__ __launch_bounds__(NT) void k_cbt(const float* __restrict__ emb, float* __restrict__ cbn,
                                            unsigned short* __restrict__ cbh, unsigned short* __restrict__ cbl) {
    const int k = blockIdx.x, t = threadIdx.x, w = t >> 6, lane = t & 63;
    const float2* e2 = (const float2*)(emb + (size_t)k * D);
    float2 v = e2[t];
    float ss = wsum(v.x*v.x + v.y*v.y);
    __shared__ float part[4]; __shared__ float sinv;
    if (lane == 0) part[w] = ss;
    __syncthreads();
    if (t == 0) sinv = 1.0f / fmaxf(sqrtf(part[0]+part[1]+part[2]+part[3]), 1e-12f);
    __syncthreads();
    float iv = sinv;
    float x = v.x * iv, y = v.y * iv;
    size_t o = (size_t)k * D + 2 * t;
    cbn[o] = x; cbn[o + 1] = y;
    unsigned short hx = f2bf(x), hy = f2bf(y);
    cbh[o] = hx; cbh[o + 1] = hy;
    cbl[o] = f2bf(x - bf2f(hx)); cbl[o + 1] = f2bf(y - bf2f(hy));
}

// ---------------- K3: embT hi/lo bf16 [D][K] (B-operand for the quant GEMM)
__global__ __launch_bounds__(NT) void k_embT(const float* __restrict__ emb,
                                             unsigned short* __restrict__ eh, unsigned short* __restrict__ el) {
    __shared__ float tile[64][65];
    const int bid = blockIdx.x;
    const int k0 = (bid & 15) * 64, d0 = (bid >> 4) * 64;
    const int t = threadIdx.x;
    const float4* e4 = (const float4*)emb;
    for (int idx = t; idx < 1024; idx += NT) {
        int kr = idx >> 4, c4 = idx & 15;
        float4 v = e4[(size_t)(k0 + kr) * (D / 4) + (d0 >> 2) + c4];
        tile[kr][c4*4+0] = v.x; tile[kr][c4*4+1] = v.y; tile[kr][c4*4+2] = v.z; tile[kr][c4*4+3] = v.w;
    }
    __syncthreads();
    for (int idx = t; idx < 1024; idx += NT) {
        int dr = idx >> 4, k4 = idx & 15;
        ushort4 h, l;
        float x0 = tile[k4*4+0][dr], x1 = tile[k4*4+1][dr], x2 = tile[k4*4+2][dr], x3 = tile[k4*4+3][dr];
        h.x = f2bf(x0); h.y = f2bf(x1); h.z = f2bf(x2); h.w = f2bf(x3);
        l.x = f2bf(x0 - bf2f(h.x)); l.y = f2bf(x1 - bf2f(h.y));
        l.z = f2bf(x2 - bf2f(h.z)); l.w = f2bf(x3 - bf2f(h.w));
        size_t o = (size_t)(d0 + dr) * KCB + k0 + k4 * 4;
        *(ushort4*)&eh[o] = h;
        *(ushort4*)&el[o] = l;
    }
}

// ---------------- K4: attention MFMA (3-pass hi/lo) + softmax + candidates + soft/avg outputs
// block = 32 rows x full K=1024; wave w owns cols [w*256, w*256+256)
__global__ __launch_bounds__(NT, 2) void k_attn(
    const float* __restrict__ lat, const unsigned short* __restrict__ cbh,
    const unsigned short* __restrict__ cbl, const float* __restrict__ inv_ws,
    float* __restrict__ soft_out, float* __restrict__ avg_ws,
    unsigned* __restrict__ cand, unsigned* __restrict__ cand_cnt)
{
    __shared__ __align__(16) unsigned short lnh[32 * AS];
    __shared__ __align__(16) unsigned short lnl[32 * AS];
    __shared__ float s_rr[4][32];
    __shared__ float s_rowmax[32], s_rinv[32];
    const int t = threadIdx.x, w = t >> 6, lane = t & 63;
    const int quad = lane >> 4, c16 = lane & 15;
    const int b0 = blockIdx.x * 32;

    f4 acc[2][16];
    #pragma unroll
    for (int i = 0; i < 2; ++i)
        #pragma unroll
        for (int j = 0; j < 16; ++j) acc[i][j] = (f4){0.f, 0.f, 0.f, 0.f};

    const float4* lat4 = (const float4*)lat;
    for (int c = 0; c < 2; ++c) {
        if (c) __syncthreads();
        #pragma unroll
        for (int ii = 0; ii < 8; ++ii) {             // stage 32x256 fp32 -> hi/lo bf16 LDS
            int idx = t + ii * NT;
            int row = idx >> 6, c4 = idx & 63;
            float4 v = lat4[(size_t)(b0 + row) * 128 + c * 64 + c4];
            float iv = inv_ws[b0 + row];
            float x0 = v.x*iv, x1 = v.y*iv, x2 = v.z*iv, x3 = v.w*iv;
            ushort4 h, l;
            h.x = f2bf(x0); h.y = f2bf(x1); h.z = f2bf(x2); h.w = f2bf(x3);
            l.x = f2bf(x0 - bf2f(h.x)); l.y = f2bf(x1 - bf2f(h.y));
            l.z = f2bf(x2 - bf2f(h.z)); l.w = f2bf(x3 - bf2f(h.w));
            *(ushort4*)&lnh[row * AS + c4 * 4] = h;
            *(ushort4*)&lnl[row * AS + c4 * 4] = l;
        }
        __syncthreads();
        for (int kk = 0; kk < 256; kk += 32) {
            s8 ah0 = *(const s8*)&lnh[c16 * AS + kk + quad * 8];
            s8 ah1 = *(const s8*)&lnh[(16 + c16) * AS + kk + quad * 8];
            s8 al0 = *(const s8*)&lnl[c16 * AS + kk + quad * 8];
            s8 al1 = *(const s8*)&lnl[(16 + c16) * AS + kk + quad * 8];
            const size_t kg = (size_t)(c * 256 + kk + quad * 8);
            const unsigned short* bhp = cbh + (size_t)(w * 256 + c16) * D + kg;
            const unsigned short* blp = cbl + (size_t)(w * 256 + c16) * D + kg;
            #pragma unroll 4
            for (int nt = 0; nt < 16; ++nt) {
                s8 bh = *(const s8*)(bhp + (size_t)nt * 16 * D);
                s8 bl = *(const s8*)(blp + (size_t)nt * 16 * D);
                acc[0][nt] = __builtin_amdgcn_mfma_f32_16x16x32_bf16(ah0, bh, acc[0][nt], 0, 0, 0);
                acc[1][nt] = __builtin_amdgcn_mfma_f32_16x16x32_bf16(ah1, bh, acc[1][nt], 0, 0, 0);
                acc[0][nt] = __builtin_amdgcn_mfma_f32_16x16x32_bf16(ah0, bl, acc[0][nt], 0, 0, 0);
                acc[1][nt] = __builtin_amdgcn_mfma_f32_16x16x32_bf16(ah1, bl, acc[1][nt], 0, 0, 0);
                acc[0][nt] = __builtin_amdgcn_mfma_f32_16x16x32_bf16(al0, bh, acc[0][nt], 0, 0, 0);
                acc[1][nt] = __builtin_amdgcn_mfma_f32_16x16x32_bf16(al1, bh, acc[1][nt], 0, 0, 0);
            }
        }
    }
    // C/D layout: row = mt*16 + quad*4 + reg, col = w*256 + nt*16 + c16
    // ---- row max (16-lane butterfly within quad groups, then 4 waves via LDS)
    float rmax[2][4];
    #pragma unroll
    for (int mt = 0; mt < 2; ++mt)
        #pragma unroll
        for (int rg = 0; rg < 4; ++rg) {
            float m = acc[mt][0][rg];
            #pragma unroll
            for (int nt = 1; nt < 16; ++nt) m = fmaxf(m, acc[mt][nt][rg]);
            #pragma unroll
            for (int off = 1; off < 16; off <<= 1) m = fmaxf(m, __shfl_xor(m, off, 64));
            rmax[mt][rg] = m;
        }
    if (c16 == 0) {
        #pragma unroll
        for (int mt = 0; mt < 2; ++mt)
            #pragma unroll
            for (int rg = 0; rg < 4; ++rg) s_rr[w][mt * 16 + quad * 4 + rg] = rmax[mt][rg];
    }
    __syncthreads();
    if (t < 32) s_rowmax[t] = fmaxf(fmaxf(s_rr[0][t], s_rr[1][t]), fmaxf(s_rr[2][t], s_rr[3][t]));
    __syncthreads();
    // ---- candidate emission (true argmax provably within rowmax - EPS2 of MFMA values)
    #pragma unroll
    for (int mt = 0; mt < 2; ++mt)
        #pragma unroll
        for (int nt = 0; nt < 16; ++nt)
            #pragma unroll
            for (int rg = 0; rg < 4; ++rg) {
                int r = mt * 16 + quad * 4 + rg;
                if (acc[mt][nt][rg] >= s_rowmax[r] - EPS2) {
                    unsigned idx = atomicAdd(cand_cnt, 1u);
                    if (idx < CAND_CAP)
                        cand[idx] = ((unsigned)(b0 + r) << 10) | (unsigned)(w * 256 + nt * 16 + c16);
                }
            }
    // ---- exp + row sums
    float rsum[2][4];
    #pragma unroll
    for (int mt = 0; mt < 2; ++mt)
        #pragma unroll
        for (int rg = 0; rg < 4; ++rg) {
            int r = mt * 16 + quad * 4 + rg;
            float rm = s_rowmax[r];
            float s = 0.f;
            #pragma unroll
            for (int nt = 0; nt < 16; ++nt) {
                float e = __expf(10.0f * (acc[mt][nt][rg] - rm));
                acc[mt][nt][rg] = e; s += e;
            }
            #pragma unroll
            for (int off = 1; off < 16; off <<= 1) s += __shfl_xor(s, off, 64);
            rsum[mt][rg] = s;
        }
    __syncthreads();
    if (c16 == 0) {
        #pragma unroll
        for (int mt = 0; mt < 2; ++mt)
            #pragma unroll
            for (int rg = 0; rg < 4; ++rg) s_rr[w][mt * 16 + quad * 4 + rg] = rsum[mt][rg];
    }
    __syncthreads();
    if (t < 32) s_rinv[t] = 1.0f / (s_rr[0][t] + s_rr[1][t] + s_rr[2][t] + s_rr[3][t]);
    __syncthreads();
    // ---- write soft_assign + per-block avg_probs partials (waves own disjoint cols)
    #pragma unroll
    for (int nt = 0; nt < 16; ++nt) {
        float colacc = 0.f;
        #pragma unroll
        for (int mt = 0; mt < 2; ++mt)
            #pragma unroll
            for (int rg = 0; rg < 4; ++rg) {
                int r = mt * 16 + quad * 4 + rg;
                float sres = acc[mt][nt][rg] * s_rinv[r];
                soft_out[(size_t)(b0 + r) * KCB + w * 256 + nt * 16 + c16] = sres;
                colacc += sres;
            }
        colacc += __shfl_xor(colacc, 16, 64);
        colacc += __shfl_xor(colacc, 32, 64);
        if (lane < 16) atomicAdd(avg_ws + w * 256 + nt * 16 + lane, colacc);
    }
}

// ---------------- K5: exact fp32 dot for each candidate; atomicMax packed (val, 1023-k)
__global__ __launch_bounds__(NT) void k_fixcand(
    const float* __restrict__ lat, const float* __restrict__ cbn, const float* __restrict__ inv_ws,
    const unsigned* __restrict__ cand, const unsigned* __restrict__ cand_cnt,
    unsigned long long* __restrict__ rowwin)
{
    const int t = threadIdx.x, w = t >> 6, lane = t & 63;
    const unsigned wid = blockIdx.x * 4 + w;
    unsigned cnt = cand_cnt[0]; if (cnt > CAND_CAP) cnt = CAND_CAP;
    const float4* lat4 = (const float4*)lat;
    const float4* cb4  = (const float4*)cbn;
    for (unsigned i = wid; i < cnt; i += 512) {
        unsigned e = cand[i];
        int row = (int)(e >> 10); int k = (int)(e & 1023u);
        float4 a0 = lat4[(size_t)row * 128 + lane * 2];
        float4 a1 = lat4[(size_t)row * 128 + lane * 2 + 1];
        float4 b0 = cb4[(size_t)k * 128 + lane * 2];
        float4 b1 = cb4[(size_t)k * 128 + lane * 2 + 1];
        float s = a0.x*b0.x + a0.y*b0.y + a0.z*b0.z + a0.w*b0.w
                + a1.x*b1.x + a1.y*b1.y + a1.z*b1.z + a1.w*b1.w;
        s = wsum(s);
        if (lane == 0) {
            float val = s * inv_ws[row];     // max attention > 0 w.p. 1 - 2^-1024
            unsigned long long key = (((unsigned long long)__float_as_uint(val)) << 32)
                                   | (unsigned long long)(unsigned)(1023 - k);
            atomicMax(rowwin + row, key);
        }
    }
}

// ---------------- K6: argm (exact), hard_quantized gather, cluster-metric partials
__global__ __launch_bounds__(NT) void k_hq(
    const float* __restrict__ emb, const unsigned long long* __restrict__ rowwin,
    float* __restrict__ argm_out, float* __restrict__ hq_out, float* __restrict__ clu_part)
{
    const int t = threadIdx.x, w = t >> 6, lane = t & 63;
    const int row = blockIdx.x * 4 + w;
    unsigned long long key = rowwin[row];
    int k = 1023 - (int)(key & 0xFFFFFFFFull);
    float val = __uint_as_float((unsigned)(key >> 32));
    const float4* e4 = (const float4*)emb;
    float4 v0 = e4[(size_t)k * 128 + lane * 2], v1 = e4[(size_t)k * 128 + lane * 2 + 1];
    float4* h4 = (float4*)hq_out;
    h4[(size_t)row * 128 + lane * 2] = v0;
    h4[(size_t)row * 128 + lane * 2 + 1] = v1;
    __shared__ float pv[4];
    if (lane == 0) { argm_out[row] = (float)k; pv[w] = val; }
    __syncthreads();
    if (t == 0) atomicAdd(clu_part + (blockIdx.x & 255), pv[0] + pv[1] + pv[2] + pv[3]);
}

// ---------------- K7: quantized = soft @ emb via MFMA (3-pass hi/lo), fused SSE
// block = 32 rows x full D=512; wave w owns d in [w*128, w*128+128); K staged in 4 chunks
__global__ __launch_bounds__(NT, 2) void k_quant(
    const float* __restrict__ lat, const unsigned short* __restrict__ eTh,
    const unsigned short* __restrict__ eTl, const float* __restrict__ soft_in,
    const float* __restrict__ inv_ws, float* __restrict__ q_out, float* __restrict__ sse_ws)
{
    __shared__ __align__(16) unsigned short sfh[32 * AS];
    __shared__ __align__(16) unsigned short sfl[32 * AS];
    __shared__ float part[4];
    const int t = threadIdx.x, w = t >> 6, lane = t & 63;
    const int quad = lane >> 4, c16 = lane & 15;
    const int b0 = blockIdx.x * 32;

    f4 acc[2][8];
    #pragma unroll
    for (int i = 0; i < 2; ++i)
        #pragma unroll
        for (int j = 0; j < 8; ++j) acc[i][j] = (f4){0.f, 0.f, 0.f, 0.f};

    const float4* s4 = (const float4*)soft_in;
    for (int c = 0; c < 4; ++c) {
        if (c) __syncthreads();
        #pragma unroll
        for (int ii = 0; ii < 8; ++ii) {
            int idx = t + ii * NT;
            int row = idx >> 6, c4 = idx & 63;
            float4 v = s4[(size_t)(b0 + row) * 256 + c * 64 + c4];
            ushort4 h, l;
            h.x = f2bf(v.x); h.y = f2bf(v.y); h.z = f2bf(v.z); h.w = f2bf(v.w);
            l.x = f2bf(v.x - bf2f(h.x)); l.y = f2bf(v.y - bf2f(h.y));
            l.z = f2bf(v.z - bf2f(h.z)); l.w = f2bf(v.w - bf2f(h.w));
            *(ushort4*)&sfh[row * AS + c4 * 4] = h;
            *(ushort4*)&sfl[row * AS + c4 * 4] = l;
        }
        __syncthreads();
        for (int kk = 0; kk < 256; kk += 32) {
            s8 ah0 = *(const s8*)&sfh[c16 * AS + kk + quad * 8];
            s8 ah1 = *(const s8*)&sfh[(16 + c16) * AS + kk + quad * 8];
            s8 al0 = *(const s8*)&sfl[c16 * AS + kk + quad * 8];
            s8 al1 = *(const s8*)&sfl[(16 + c16) * AS + kk + quad * 8];
            const size_t kg = (size_t)(c * 256 + kk + quad * 8);
            const unsigned short* bhp = eTh + (size_t)(w * 128 + c16) * KCB + kg;
            const unsigned short* blp = eTl + (size_t)(w * 128 + c16) * KCB + kg;
            #pragma unroll 4
            for (int nt = 0; nt < 8; ++nt) {
                s8 bh = *(const s8*)(bhp + (size_t)nt * 16 * KCB);
                s8 bl = *(const s8*)(blp + (size_t)nt * 16 * KCB);
                acc[0][nt] = __builtin_amdgcn_mfma_f32_16x16x32_bf16(ah0, bh, acc[0][nt], 0, 0, 0);
                acc[1][nt] = __builtin_amdgcn_mfma_f32_16x16x32_bf16(ah1, bh, acc[1][nt], 0, 0, 0);
                acc[0][nt] = __builtin_amdgcn_mfma_f32_16x16x32_bf16(ah0, bl, acc[0][nt], 0, 0, 0);
                acc[1][nt] = __builtin_amdgcn_mfma_f32_16x16x32_bf16(ah1, bl, acc[1][nt], 0, 0, 0);
                acc[0][nt] = __builtin_amdgcn_mfma_f32_16x16x32_bf16(al0, bh, acc[0][nt], 0, 0, 0);
                acc[1][nt] = __builtin_amdgcn_mfma_f32_16x16x32_bf16(al1, bh, acc[1][nt], 0, 0, 0);
            }
        }
    }
    float sse = 0.f;
    #pragma unroll
    for (int mt = 0; mt < 2; ++mt)
        #pragma unroll
        for (int nt = 0; nt < 8; ++nt)
            #pragma unroll
            for (int rg = 0; rg < 4; ++rg) {
                int r = mt * 16 + quad * 4 + rg;
                int d = w * 128 + nt * 16 + c16;
                float q = acc[mt][nt][rg];
                q_out[(size_t)(b0 + r) * D + d] = q;
                float lnv = lat[(size_t)(b0 + r) * D + d] * inv_ws[b0 + r];
                float df = q - lnv;
                sse += df * df;
            }
    sse = wsum(sse);
    if (lane == 0) part[w] = sse;
    __syncthreads();
    if (t == 0) atomicAdd(sse_ws, part[0] + part[1] + part[2] + part[3]);
}

// ---------------- K8: scalars
__global__ __launch_bounds__(NT) void k_final(
    const float* __restrict__ avg_ws, const float* __restrict__ sse_ws,
    const float* __restrict__ clu_part,
    float* __restrict__ out_vq, float* __restrict__ out_ent, float* __restrict__ out_cm,
    float invB, float invBD)
{
    const int t = threadIdx.x, w = t >> 6, lane = t & 63;
    float ent = 0.f;
    for (int i = t; i < KCB; i += NT) { float p = avg_ws[i] * invB; ent -= p * logf(p + 1e-10f); }
    ent = wsum(ent);
    float cl = clu_part[t];
    cl = wsum(cl);
    __shared__ float pe[4], pc[4];
    if (lane == 0) { pe[w] = ent; pc[w] = cl; }
    __syncthreads();
    if (t == 0) {
        *out_ent = pe[0] + pe[1] + pe[2] + pe[3];
        *out_vq  = 1.25f * sse_ws[0] * invBD;     // (BETA + 1) * MSE
        *out_cm  = (pc[0] + pc[1] + pc[2] + pc[3]) * invB;
    }
}

extern "C" void kernel_launch(void* const* d_in, const int* in_sizes, int n_in,
                              void* d_out, int out_size, void* d_ws, size_t ws_size,
                              hipStream_t stream)
{
    const float* lat = (const float*)d_in[0];
    const float* emb = (const float*)d_in[1];
    const int B = in_sizes[0] / D;               // 16384
    float* out = (float*)d_out;

    // output layout: quantized | vq_loss | entropy | argm | hard_quantized | soft_assign | cluster_metric
    const size_t vq_off   = (size_t)B * D;
    const size_t ent_off  = vq_off + 1;
    const size_t argm_off = vq_off + 2;
    const size_t hq_off   = argm_off + (size_t)B;
    const size_t soft_off = hq_off + (size_t)B * D;
    const size_t cm_off   = soft_off + (size_t)B * KCB;

    // workspace layout (~7.5 MB)
    float* ws = (float*)d_ws;
    float* cbn = ws;                                             // K*D fp32       (2 MB)
    unsigned short* cbh = (unsigned short*)(cbn + (size_t)KCB * D);   // K*D bf16  (1 MB)
    unsigned short* cbl = cbh + (size_t)KCB * D;                 // 1 MB
    unsigned short* eTh = cbl + (size_t)KCB * D;                 // D*K bf16       (1 MB)
    unsigned short* eTl = eTh + (size_t)D * KCB;                 // 1 MB
    float* inv_ws   = (float*)(eTl + (size_t)D * KCB);           // B
    float* avg_ws   = inv_ws + B;                                // K
    float* clu_part = avg_ws + KCB;                              // 256
    float* sse_ws   = clu_part + 256;                            // 1 (+1 pad)
    unsigned long long* rowwin = (unsigned long long*)(sse_ws + 2);   // B u64 (8B-aligned)
    unsigned* cand     = (unsigned*)(rowwin + B);                // CAND_CAP u32
    unsigned* cand_cnt = cand + CAND_CAP;                        // 1

    k_init<<<64, NT, 0, stream>>>(rowwin, avg_ws, clu_part, cand_cnt, sse_ws, B);
    k_norms<<<B / 4, NT, 0, stream>>>(lat, inv_ws);
    k_cbt<<<KCB, NT, 0, stream>>>(emb, cbn, cbh, cbl);
    k_embT<<<128, NT, 0, stream>>>(emb, eTh, eTl);
    k_attn<<<B / 32, NT, 0, stream>>>(lat, cbh, cbl, inv_ws,
                                      out + soft_off, avg_ws, cand, cand_cnt);
    k_fixcand<<<128, NT, 0, stream>>>(lat, cbn, inv_ws, cand, cand_cnt, rowwin);
    k_hq<<<B / 4, NT, 0, stream>>>(emb, rowwin, out + argm_off, out + hq_off, clu_part);
    k_quant<<<B / 32, NT, 0, stream>>>(lat, eTh, eTl, out + soft_off, inv_ws, out, sse_ws);
    k_final<<<1, NT, 0, stream>>>(avg_ws, sse_ws, clu_part,
                                  out + vq_off, out + ent_off, out + cm_off,
                                  1.0f / (float)B, 1.0f / ((float)B * (float)D));
}